// Round 16
// baseline (3476.576 us; speedup 1.0000x reference)
//
#include <hip/hip_runtime.h>

typedef unsigned int u32;

#define NPTS 65536
#define G    24
#define NC   (G*G*G)      // 13824 cells, ~4.7 pts/cell UNIFORM after CDF transform
#define CPT  14           // ceil(NC/1024) for the scan

// ws byte offsets (total ~2.32 MB)
#define CNTA_OFF 0u
#define CNTB_OFF (CNTA_OFF + NC*4u)
#define HDRA_OFF (CNTB_OFF + NC*4u)        // uint2 (start,count) per cell, 8-aligned
#define HDRB_OFF (HDRA_OFF + NC*8u)
#define SRTA_OFF (HDRB_OFF + NC*8u)
#define SRTB_OFF (SRTA_OFF + NPTS*16u)

__device__ __forceinline__ int clampi(int v, int lo, int hi) {
    return v < lo ? lo : (v > hi ? hi : v);
}

// Per-axis Gaussian CDF binning: coords are iid N(0,10) (setup_inputs), so
// u = Phi(x/10) is EXACTLY uniform on [0,1] per axis and independent -> the
// transformed cloud is uniform in the cube -> every cell holds ~4.7 points.
// Correctness does NOT depend on the distribution assumption: any monotone
// transform + consistent boundary table gives exact NN; uniformity only
// affects speed.
__device__ __forceinline__ void cell3(float x, float y, float z,
                                      int& cx, int& cy, int& cz) {
    const float kk = 0.07071067811865475f;   // 1/(10*sqrt(2))
    cx = clampi((int)(0.5f * erfcf(-x * kk) * (float)G), 0, G - 1);
    cy = clampi((int)(0.5f * erfcf(-y * kk) * (float)G), 0, G - 1);
    cz = clampi((int)(0.5f * erfcf(-z * kk) * (float)G), 0, G - 1);
}

// ---- 1. per-cell histogram ----
__global__ __launch_bounds__(256) void count_kernel(
    const float* __restrict__ A, const float* __restrict__ B,
    unsigned char* __restrict__ ws)
{
    const int i = blockIdx.x * 256 + threadIdx.x;   // 0..131071
    const int cloud = i >= NPTS;
    const int p = i & (NPTS - 1);
    const float* __restrict__ P = cloud ? B : A;
    u32* cnt = (u32*)(ws + (cloud ? CNTB_OFF : CNTA_OFF));
    int cx, cy, cz;
    cell3(P[p * 3], P[p * 3 + 1], P[p * 3 + 2], cx, cy, cz);
    atomicAdd(&cnt[(cz * G + cy) * G + cx], 1u);
}

// ---- 2. exclusive scan -> hdr[c] = (start, count) ----
__global__ __launch_bounds__(1024) void scan_kernel(unsigned char* __restrict__ ws)
{
    const int cloud = blockIdx.x;
    const u32* cnt = (const u32*)(ws + (cloud ? CNTB_OFF : CNTA_OFF));
    uint2* hdr = (uint2*)(ws + (cloud ? HDRB_OFF : HDRA_OFF));
    const int t = threadIdx.x;

    u32 s = 0;
#pragma unroll
    for (int k = 0; k < CPT; ++k) {
        const int c = t * CPT + k;
        s += (c < NC) ? cnt[c] : 0u;
    }
    __shared__ u32 lds[1024];
    lds[t] = s;
    __syncthreads();
    for (int o = 1; o < 1024; o <<= 1) {
        const u32 v = (t >= o) ? lds[t - o] : 0u;
        __syncthreads();
        lds[t] += v;
        __syncthreads();
    }
    u32 run = lds[t] - s;
#pragma unroll
    for (int k = 0; k < CPT; ++k) {
        const int c = t * CPT + k;
        if (c < NC) {
            const u32 n = cnt[c];
            hdr[c] = make_uint2(run, n);
            run += n;
        }
    }
}

// ---- 3. scatter into cell-sorted order (cnt doubles as down-cursor) ----
__global__ __launch_bounds__(256) void scatter_kernel(
    const float* __restrict__ A, const float* __restrict__ B,
    unsigned char* __restrict__ ws)
{
    const int i = blockIdx.x * 256 + threadIdx.x;
    const int cloud = i >= NPTS;
    const int p = i & (NPTS - 1);
    const float* __restrict__ P = cloud ? B : A;
    u32* cnt = (u32*)(ws + (cloud ? CNTB_OFF : CNTA_OFF));
    const uint2* hdr = (const uint2*)(ws + (cloud ? HDRB_OFF : HDRA_OFF));
    float4* srt = (float4*)(ws + (cloud ? SRTB_OFF : SRTA_OFF));

    const float x = P[p * 3], y = P[p * 3 + 1], z = P[p * 3 + 2];
    int cx, cy, cz;
    cell3(x, y, z, cx, cy, cz);
    const int c = (cz * G + cy) * G + cx;
    const u32 old = atomicSub(&cnt[c], 1u);          // count .. 1, unique
    srt[hdr[c].x + old - 1u] = make_float4(x, y, z, 0.0f);
}

// ---- 4. NN query, thread per query ----
// Fast path: all 27 ring-0/1 headers prefetched (independent uint2 loads ->
// one latency), then ~128 contiguous point loads. Euclidean break bound from
// the boundary table XB (distance from q to the inner scanned box), with
// 1e-3 conservative slack (only reduces pruning -> exactness preserved).
__global__ __launch_bounds__(256) void query_kernel(
    const unsigned char* __restrict__ ws, float* __restrict__ out)
{
    __shared__ float XB[G + 1];   // Euclidean lower boundary of cell i
    if (threadIdx.x <= G) {
        float v;
        if (threadIdx.x == 0)       v = -3e37f;
        else if (threadIdx.x == G)  v =  3e37f;
        else v = 14.142135623730951f *
                 erfinvf(2.0f * (float)threadIdx.x / (float)G - 1.0f);
        XB[threadIdx.x] = v;
    }
    __syncthreads();

    const int gid  = blockIdx.x * 256 + threadIdx.x;   // 0..131071
    const int dirB = gid >= NPTS;    // 0: q=sortedA, DB=B ; 1: q=sortedB, DB=A
    const int qi   = gid & (NPTS - 1);

    const uint2*  __restrict__ hdr = (const uint2*)(ws + (dirB ? HDRA_OFF : HDRB_OFF));
    const float4* __restrict__ dbp = (const float4*)(ws + (dirB ? SRTA_OFF : SRTB_OFF));
    const float4* __restrict__ qp  = (const float4*)(ws + (dirB ? SRTB_OFF : SRTA_OFF));

    const float4 q = qp[qi];
    int cx, cy, cz;
    cell3(q.x, q.y, q.z, cx, cy, cz);

    float best = 3.4e38f;

    // fast path: rings 0..1 (27 cells), headers batched
    uint2 h[27];
#pragma unroll
    for (int i = 0; i < 27; ++i) {
        const int dx = i % 3 - 1, dy = (i / 3) % 3 - 1, dz = i / 9 - 1;
        const int x = cx + dx, y = cy + dy, z = cz + dz;
        const bool ok = (unsigned)x < G && (unsigned)y < G && (unsigned)z < G;
        h[i] = ok ? hdr[(z * G + y) * G + x] : make_uint2(0u, 0u);
    }
#pragma unroll
    for (int i = 0; i < 27; ++i) {
        const u32 s0 = h[i].x, n = h[i].y;
        for (u32 k = s0; k < s0 + n; ++k) {
            const float4 p = dbp[k];
            const float ddx = q.x - p.x, ddy = q.y - p.y, ddz = q.z - p.z;
            best = fminf(best, fmaf(ddx, ddx, fmaf(ddy, ddy, ddz * ddz)));
        }
    }

    // rings r>=2 with exact box lower bound (rare after uniformization)
    for (int r = 2; r < G; ++r) {
        const float lb = fminf(
            fminf(fminf(q.x - XB[max(cx - r + 1, 0)], XB[min(cx + r, G)] - q.x),
                  fminf(q.y - XB[max(cy - r + 1, 0)], XB[min(cy + r, G)] - q.y)),
            fminf(q.z - XB[max(cz - r + 1, 0)], XB[min(cz + r, G)] - q.z)) - 1e-3f;
        if (lb > 0.0f && lb * lb >= best) break;

        for (int dz = -r; dz <= r; ++dz) {
            const int z = cz + dz;
            if ((unsigned)z >= G) continue;
            for (int dy = -r; dy <= r; ++dy) {
                const int y = cy + dy;
                if ((unsigned)y >= G) continue;
                const bool face = (dz == -r || dz == r || dy == -r || dy == r);
                const int step = face ? 1 : 2 * r;
                for (int dx = -r; dx <= r; dx += step) {
                    const int x = cx + dx;
                    if ((unsigned)x >= G) continue;
                    const uint2 hh = hdr[(z * G + y) * G + x];
                    for (u32 k = hh.x; k < hh.x + hh.y; ++k) {
                        const float4 p = dbp[k];
                        const float ddx = q.x - p.x, ddy = q.y - p.y, ddz = q.z - p.z;
                        best = fminf(best, fmaf(ddx, ddx, fmaf(ddy, ddy, ddz * ddz)));
                    }
                }
            }
        }
    }

    // block reduce: sum(best)/NPTS
    float v = best;
#pragma unroll
    for (int o = 32; o > 0; o >>= 1)
        v += __shfl_down(v, o, 64);
    __shared__ float ws2[4];
    const int lane = threadIdx.x & 63;
    const int wid  = threadIdx.x >> 6;
    if (lane == 0) ws2[wid] = v;
    __syncthreads();
    if (threadIdx.x == 0)
        atomicAdd(out, (ws2[0] + ws2[1] + ws2[2] + ws2[3]) * (1.0f / (float)NPTS));
}

// ============================================================================
extern "C" void kernel_launch(void* const* d_in, const int* in_sizes, int n_in,
                              void* d_out, int out_size, void* d_ws, size_t ws_size,
                              hipStream_t stream)
{
    const float* A = (const float*)d_in[0];   // pc0 (65536,3) f32
    const float* B = (const float*)d_in[1];   // pc1 (65536,3) f32
    float* out = (float*)d_out;               // scalar f32
    unsigned char* ws = (unsigned char*)d_ws;

    hipMemsetAsync(ws + CNTA_OFF, 0, 2u * NC * 4u, stream);   // cntA + cntB
    hipMemsetAsync(out, 0, sizeof(float), stream);

    count_kernel  <<<(2 * NPTS) / 256, 256, 0, stream>>>(A, B, ws);
    scan_kernel   <<<2, 1024, 0, stream>>>(ws);
    scatter_kernel<<<(2 * NPTS) / 256, 256, 0, stream>>>(A, B, ws);
    query_kernel  <<<(2 * NPTS) / 256, 256, 0, stream>>>(ws, out);
}

// Round 17
// 3203.146 us; speedup vs baseline: 1.0854x; 1.0854x over previous
//
#include <hip/hip_runtime.h>

typedef unsigned int u32;

#define NPTS 65536
#define G    24
#define NC   (G*G*G)      // 13824 cells, ~4.7 pts/cell UNIFORM after CDF transform
#define CPT  14           // ceil(NC/1024) for the scan

// ws byte offsets (total ~2.32 MB)
#define CNTA_OFF 0u
#define CNTB_OFF (CNTA_OFF + NC*4u)
#define HDRA_OFF (CNTB_OFF + NC*4u)        // uint2 (start,count) per cell, 8-aligned
#define HDRB_OFF (HDRA_OFF + NC*8u)
#define SRTA_OFF (HDRB_OFF + NC*8u)
#define SRTB_OFF (SRTA_OFF + NPTS*16u)

__device__ __forceinline__ int clampi(int v, int lo, int hi) {
    return v < lo ? lo : (v > hi ? hi : v);
}

// Per-axis Gaussian CDF binning (r16-validated, absmax 0.0): coords are iid
// N(0,10), so u = Phi(x/10) is uniform -> ~4.7 pts in EVERY cell. Exactness
// never depends on the distribution; only speed does.
__device__ __forceinline__ void cell3(float x, float y, float z,
                                      int& cx, int& cy, int& cz) {
    const float kk = 0.07071067811865475f;   // 1/(10*sqrt(2))
    cx = clampi((int)(0.5f * erfcf(-x * kk) * (float)G), 0, G - 1);
    cy = clampi((int)(0.5f * erfcf(-y * kk) * (float)G), 0, G - 1);
    cz = clampi((int)(0.5f * erfcf(-z * kk) * (float)G), 0, G - 1);
}

// ---- 1. per-cell histogram (verbatim r16) ----
__global__ __launch_bounds__(256) void count_kernel(
    const float* __restrict__ A, const float* __restrict__ B,
    unsigned char* __restrict__ ws)
{
    const int i = blockIdx.x * 256 + threadIdx.x;   // 0..131071
    const int cloud = i >= NPTS;
    const int p = i & (NPTS - 1);
    const float* __restrict__ P = cloud ? B : A;
    u32* cnt = (u32*)(ws + (cloud ? CNTB_OFF : CNTA_OFF));
    int cx, cy, cz;
    cell3(P[p * 3], P[p * 3 + 1], P[p * 3 + 2], cx, cy, cz);
    atomicAdd(&cnt[(cz * G + cy) * G + cx], 1u);
}

// ---- 2. exclusive scan -> hdr[c] = (start, count) (verbatim r16) ----
__global__ __launch_bounds__(1024) void scan_kernel(unsigned char* __restrict__ ws)
{
    const int cloud = blockIdx.x;
    const u32* cnt = (const u32*)(ws + (cloud ? CNTB_OFF : CNTA_OFF));
    uint2* hdr = (uint2*)(ws + (cloud ? HDRB_OFF : HDRA_OFF));
    const int t = threadIdx.x;

    u32 s = 0;
#pragma unroll
    for (int k = 0; k < CPT; ++k) {
        const int c = t * CPT + k;
        s += (c < NC) ? cnt[c] : 0u;
    }
    __shared__ u32 lds[1024];
    lds[t] = s;
    __syncthreads();
    for (int o = 1; o < 1024; o <<= 1) {
        const u32 v = (t >= o) ? lds[t - o] : 0u;
        __syncthreads();
        lds[t] += v;
        __syncthreads();
    }
    u32 run = lds[t] - s;
#pragma unroll
    for (int k = 0; k < CPT; ++k) {
        const int c = t * CPT + k;
        if (c < NC) {
            const u32 n = cnt[c];
            hdr[c] = make_uint2(run, n);
            run += n;
        }
    }
}

// ---- 3. scatter into cell-sorted order (verbatim r16) ----
__global__ __launch_bounds__(256) void scatter_kernel(
    const float* __restrict__ A, const float* __restrict__ B,
    unsigned char* __restrict__ ws)
{
    const int i = blockIdx.x * 256 + threadIdx.x;
    const int cloud = i >= NPTS;
    const int p = i & (NPTS - 1);
    const float* __restrict__ P = cloud ? B : A;
    u32* cnt = (u32*)(ws + (cloud ? CNTB_OFF : CNTA_OFF));
    const uint2* hdr = (const uint2*)(ws + (cloud ? HDRB_OFF : HDRA_OFF));
    float4* srt = (float4*)(ws + (cloud ? SRTB_OFF : SRTA_OFF));

    const float x = P[p * 3], y = P[p * 3 + 1], z = P[p * 3 + 2];
    int cx, cy, cz;
    cell3(x, y, z, cx, cy, cz);
    const int c = (cz * G + cy) * G + cx;
    const u32 old = atomicSub(&cnt[c], 1u);          // count .. 1, unique
    srt[hdr[c].x + old - 1u] = make_float4(x, y, z, 0.0f);
}

// ---- 4. NN query: ONE WAVE PER QUERY-CELL (cooperative) ----
// r12/r15/r16 were latency-bound: each query-thread serially chased headers
// its neighbors also needed (r16 additionally spilled h[27] to scratch,
// VGPR=48 < 54). Here the wave loads the 27-cell neighborhood ONCE:
// 9 x-contiguous segments, bounds fetched by lanes 0..8 (18 parallel loads),
// shared via shfl; candidates scanned fully packed (lane t -> candidate t,
// t+64, ...); per-query wave-min via 6 shfl_xor. All arrays static-indexed
// (no scratch). Exact-bound fallback on lane 0, probability ~0.
__global__ __launch_bounds__(256) void query_kernel(
    const unsigned char* __restrict__ ws, float* __restrict__ out)
{
    __shared__ float XB[G + 1];   // Euclidean lower boundary of cell i
    if (threadIdx.x <= G) {
        float v;
        if (threadIdx.x == 0)       v = -3e37f;
        else if (threadIdx.x == G)  v =  3e37f;
        else v = 14.142135623730951f *
                 erfinvf(2.0f * (float)threadIdx.x / (float)G - 1.0f);
        XB[threadIdx.x] = v;
    }
    __syncthreads();

    const int wv   = blockIdx.x * 4 + (threadIdx.x >> 6);   // 0..27647
    const int lane = threadIdx.x & 63;
    const int dirB = wv >= NC;       // 0: queries=A, DB=B ; 1: queries=B, DB=A
    const int c    = dirB ? wv - NC : wv;
    const int cx = c % G, cy = (c / G) % G, cz = c / (G * G);

    const uint2*  __restrict__ qhdr = (const uint2*)(ws + (dirB ? HDRB_OFF : HDRA_OFF));
    const float4* __restrict__ qp   = (const float4*)(ws + (dirB ? SRTB_OFF : SRTA_OFF));
    const uint2*  __restrict__ dhdr = (const uint2*)(ws + (dirB ? HDRA_OFF : HDRB_OFF));
    const float4* __restrict__ dbp  = (const float4*)(ws + (dirB ? SRTA_OFF : SRTB_OFF));

    const uint2 qh = qhdr[c];
    float qsum = 0.0f;

    if (qh.y != 0) {
        // segment bounds: lanes 0..8 fetch (start,end) of x-run (dy,dz)
        u32 myst = 0, myen = 0;
        if (lane < 9) {
            const int dy = lane % 3 - 1, dzz = lane / 3 - 1;
            const int y = cy + dy, z = cz + dzz;
            if ((unsigned)y < G && (unsigned)z < G) {
                const int x0 = max(cx - 1, 0), x1 = min(cx + 1, G - 1);
                const int base = (z * G + y) * G;
                const uint2 hlo = dhdr[base + x0];
                const uint2 hhi = dhdr[base + x1];
                myst = hlo.x; myen = hhi.x + hhi.y;
            }
        }
        u32 st[9], P[10];
        P[0] = 0;
#pragma unroll
        for (int s = 0; s < 9; ++s) {
            st[s] = (u32)__shfl((int)myst, s, 64);
            const u32 e = (u32)__shfl((int)myen, s, 64);
            P[s + 1] = P[s] + (e - st[s]);
        }
        const u32 T = P[9];   // total candidates (~127)

        for (u32 j = 0; j < qh.y; ++j) {
            const float4 q = qp[qh.x + j];      // broadcast load
            float best = 3.4e38f;
            for (u32 t = lane; t < T; t += 64) {
                u32 k = st[0] + t;              // static-index select chain
#pragma unroll
                for (int s = 1; s < 9; ++s)
                    if (t >= P[s]) k = st[s] + (t - P[s]);
                const float4 p = dbp[k];
                const float ddx = q.x - p.x, ddy = q.y - p.y, ddz = q.z - p.z;
                best = fminf(best, fmaf(ddx, ddx, fmaf(ddy, ddy, ddz * ddz)));
            }
#pragma unroll
            for (int m = 1; m <= 32; m <<= 1)
                best = fminf(best, __shfl_xor(best, m, 64));   // uniform now

            // exact bound: distance from q to the scanned 3x3x3 box boundary
            const float lb = fminf(fminf(
                fminf(q.x - XB[max(cx - 1, 0)], XB[min(cx + 2, G)] - q.x),
                fminf(q.y - XB[max(cy - 1, 0)], XB[min(cy + 2, G)] - q.y)),
                fminf(q.z - XB[max(cz - 1, 0)], XB[min(cz + 2, G)] - q.z)) - 1e-3f;

            if (!(lb > 0.0f && lb * lb >= best)) {
                if (lane == 0) {   // rare exact fallback: serial ring walk
                    for (int r = 2; r < G; ++r) {
                        for (int dzz = -r; dzz <= r; ++dzz) {
                            const int z = cz + dzz;
                            if ((unsigned)z >= G) continue;
                            for (int dy = -r; dy <= r; ++dy) {
                                const int y = cy + dy;
                                if ((unsigned)y >= G) continue;
                                const bool face = (dzz == -r || dzz == r || dy == -r || dy == r);
                                const int step = face ? 1 : 2 * r;
                                for (int dx = -r; dx <= r; dx += step) {
                                    const int x = cx + dx;
                                    if ((unsigned)x >= G) continue;
                                    const uint2 hh = dhdr[(z * G + y) * G + x];
                                    for (u32 k = hh.x; k < hh.x + hh.y; ++k) {
                                        const float4 p = dbp[k];
                                        const float ddx = q.x - p.x, ddy = q.y - p.y, ddz = q.z - p.z;
                                        best = fminf(best, fmaf(ddx, ddx, fmaf(ddy, ddy, ddz * ddz)));
                                    }
                                }
                            }
                        }
                        const float lbr = fminf(fminf(
                            fminf(q.x - XB[max(cx - r, 0)], XB[min(cx + r + 1, G)] - q.x),
                            fminf(q.y - XB[max(cy - r, 0)], XB[min(cy + r + 1, G)] - q.y)),
                            fminf(q.z - XB[max(cz - r, 0)], XB[min(cz + r + 1, G)] - q.z)) - 1e-3f;
                        if (lbr > 0.0f && lbr * lbr >= best) break;
                    }
                }
            }
            if (lane == 0) qsum += best;
        }
    }

    __shared__ float wsum[4];
    if (lane == 0) wsum[threadIdx.x >> 6] = qsum;
    __syncthreads();
    if (threadIdx.x == 0)
        atomicAdd(out, (wsum[0] + wsum[1] + wsum[2] + wsum[3]) * (1.0f / (float)NPTS));
}

// ============================================================================
extern "C" void kernel_launch(void* const* d_in, const int* in_sizes, int n_in,
                              void* d_out, int out_size, void* d_ws, size_t ws_size,
                              hipStream_t stream)
{
    const float* A = (const float*)d_in[0];   // pc0 (65536,3) f32
    const float* B = (const float*)d_in[1];   // pc1 (65536,3) f32
    float* out = (float*)d_out;               // scalar f32
    unsigned char* ws = (unsigned char*)d_ws;

    hipMemsetAsync(ws + CNTA_OFF, 0, 2u * NC * 4u, stream);   // cntA + cntB
    hipMemsetAsync(out, 0, sizeof(float), stream);

    count_kernel  <<<(2 * NPTS) / 256, 256, 0, stream>>>(A, B, ws);
    scan_kernel   <<<2, 1024, 0, stream>>>(ws);
    scatter_kernel<<<(2 * NPTS) / 256, 256, 0, stream>>>(A, B, ws);
    query_kernel  <<<(2 * NC) / 4, 256, 0, stream>>>(ws, out);
}

// Round 18
// 199.168 us; speedup vs baseline: 17.4555x; 16.0827x over previous
//
#include <hip/hip_runtime.h>

typedef unsigned int u32;

#define NPTS 65536
#define G    24
#define NC   (G*G*G)      // 13824 cells, ~4.7 pts/cell UNIFORM after CDF transform
#define CPT  14           // ceil(NC/1024) for the scan

// ws byte offsets (total ~2.32 MB)
#define CNTA_OFF 0u
#define CNTB_OFF (CNTA_OFF + NC*4u)
#define HDRA_OFF (CNTB_OFF + NC*4u)        // uint2 (start,count) per cell, 8-aligned
#define HDRB_OFF (HDRA_OFF + NC*8u)
#define SRTA_OFF (HDRB_OFF + NC*8u)
#define SRTB_OFF (SRTA_OFF + NPTS*16u)

__device__ __forceinline__ int clampi(int v, int lo, int hi) {
    return v < lo ? lo : (v > hi ? hi : v);
}

// Per-axis Gaussian CDF binning (r16/r17-validated, absmax 0.0). Monotone in
// the coordinate -> cell ranges of [q-rad, q+rad] bound the Euclidean ball.
__device__ __forceinline__ int cell1(float x) {
    const float kk = 0.07071067811865475f;   // 1/(10*sqrt(2))
    return clampi((int)(0.5f * erfcf(-x * kk) * (float)G), 0, G - 1);
}
__device__ __forceinline__ void cell3(float x, float y, float z,
                                      int& cx, int& cy, int& cz) {
    cx = cell1(x); cy = cell1(y); cz = cell1(z);
}

// ---- 1. per-cell histogram (verbatim r16/r17) ----
__global__ __launch_bounds__(256) void count_kernel(
    const float* __restrict__ A, const float* __restrict__ B,
    unsigned char* __restrict__ ws)
{
    const int i = blockIdx.x * 256 + threadIdx.x;   // 0..131071
    const int cloud = i >= NPTS;
    const int p = i & (NPTS - 1);
    const float* __restrict__ P = cloud ? B : A;
    u32* cnt = (u32*)(ws + (cloud ? CNTB_OFF : CNTA_OFF));
    int cx, cy, cz;
    cell3(P[p * 3], P[p * 3 + 1], P[p * 3 + 2], cx, cy, cz);
    atomicAdd(&cnt[(cz * G + cy) * G + cx], 1u);
}

// ---- 2. exclusive scan -> hdr[c] = (start, count) (verbatim r16/r17) ----
__global__ __launch_bounds__(1024) void scan_kernel(unsigned char* __restrict__ ws)
{
    const int cloud = blockIdx.x;
    const u32* cnt = (const u32*)(ws + (cloud ? CNTB_OFF : CNTA_OFF));
    uint2* hdr = (uint2*)(ws + (cloud ? HDRB_OFF : HDRA_OFF));
    const int t = threadIdx.x;

    u32 s = 0;
#pragma unroll
    for (int k = 0; k < CPT; ++k) {
        const int c = t * CPT + k;
        s += (c < NC) ? cnt[c] : 0u;
    }
    __shared__ u32 lds[1024];
    lds[t] = s;
    __syncthreads();
    for (int o = 1; o < 1024; o <<= 1) {
        const u32 v = (t >= o) ? lds[t - o] : 0u;
        __syncthreads();
        lds[t] += v;
        __syncthreads();
    }
    u32 run = lds[t] - s;
#pragma unroll
    for (int k = 0; k < CPT; ++k) {
        const int c = t * CPT + k;
        if (c < NC) {
            const u32 n = cnt[c];
            hdr[c] = make_uint2(run, n);
            run += n;
        }
    }
}

// ---- 3. scatter into cell-sorted order (verbatim r16/r17) ----
__global__ __launch_bounds__(256) void scatter_kernel(
    const float* __restrict__ A, const float* __restrict__ B,
    unsigned char* __restrict__ ws)
{
    const int i = blockIdx.x * 256 + threadIdx.x;
    const int cloud = i >= NPTS;
    const int p = i & (NPTS - 1);
    const float* __restrict__ P = cloud ? B : A;
    u32* cnt = (u32*)(ws + (cloud ? CNTB_OFF : CNTA_OFF));
    const uint2* hdr = (const uint2*)(ws + (cloud ? HDRB_OFF : HDRA_OFF));
    float4* srt = (float4*)(ws + (cloud ? SRTB_OFF : SRTA_OFF));

    const float x = P[p * 3], y = P[p * 3 + 1], z = P[p * 3 + 2];
    int cx, cy, cz;
    cell3(x, y, z, cx, cy, cz);
    const int c = (cz * G + cy) * G + cx;
    const u32 old = atomicSub(&cnt[c], 1u);          // count .. 1, unique
    srt[hdr[c].x + old - 1u] = make_float4(x, y, z, 0.0f);
}

// ---- 4. NN query: wave per query-cell, EXACT TWO-PASS BALL QUERY ----
// r16/r17 post-mortem: the 3x3x3 box bound is anisotropic in Euclidean space
// (tail slabs: best set by the WIDE dim, bound by the NARROW dim) -> 42% of
// queries fell into a lane-0 serial multi-ring walk = the ms-scale straggler
// tail (occupancy 3%). Two-pass ball query has NO bound test and NO serial
// walk: pass 1 scans the query's own x-row (wave-parallel) -> upper bound
// rad; pass 2 scans the per-dim cell range of [q-rad, q+rad] (monotone
// binning -> box covers the ball -> exact). Rows are assigned to lanes: all
// header pairs load in parallel; per-lane point runs are contiguous and
// pipeline. Work adapts to local anisotropy automatically.
__global__ __launch_bounds__(256) void query_kernel(
    const unsigned char* __restrict__ ws, float* __restrict__ out)
{
    const int wv   = blockIdx.x * 4 + (threadIdx.x >> 6);   // 0..27647
    const int lane = threadIdx.x & 63;
    const int dirB = wv >= NC;       // 0: queries=A, DB=B ; 1: queries=B, DB=A
    const int c    = dirB ? wv - NC : wv;
    const int cx = c % G, cy = (c / G) % G, cz = c / (G * G);

    const uint2*  __restrict__ qhdr = (const uint2*)(ws + (dirB ? HDRB_OFF : HDRA_OFF));
    const float4* __restrict__ qp   = (const float4*)(ws + (dirB ? SRTB_OFF : SRTA_OFF));
    const uint2*  __restrict__ dhdr = (const uint2*)(ws + (dirB ? HDRA_OFF : HDRB_OFF));
    const float4* __restrict__ dbp  = (const float4*)(ws + (dirB ? SRTA_OFF : SRTB_OFF));

    const uint2 qh = qhdr[c];
    float qsum = 0.0f;

    if (qh.y != 0) {
        // own-row segment (3 x-contiguous cells), shared by all queries here
        const int x0 = max(cx - 1, 0), x1 = min(cx + 1, G - 1);
        const int rowb = (cz * G + cy) * G;
        const uint2 h0 = dhdr[rowb + x0];          // broadcast loads
        const uint2 h1 = dhdr[rowb + x1];
        const u32 s0 = h0.x, s1 = h1.x + h1.y;

        for (u32 j = 0; j < qh.y; ++j) {
            const float4 q = qp[qh.x + j];         // broadcast load
            float best = 3.4e38f;

            // ---- pass 1: own row -> upper bound ----
            for (u32 k = s0 + lane; k < s1; k += 64) {
                const float4 p = dbp[k];
                const float dx = q.x - p.x, dy = q.y - p.y, dz = q.z - p.z;
                best = fminf(best, fmaf(dx, dx, fmaf(dy, dy, dz * dz)));
            }
#pragma unroll
            for (int m = 1; m <= 32; m <<= 1)
                best = fminf(best, __shfl_xor(best, m, 64));

            // ---- pass 2: exact ball cover ----
            const float rad = sqrtf(best) + 1e-3f;
            const int lox = cell1(q.x - rad), hix = cell1(q.x + rad);
            const int loy = cell1(q.y - rad), hiy = cell1(q.y + rad);
            const int loz = cell1(q.z - rad), hiz = cell1(q.z + rad);

            const bool skip = (lox >= x0) && (hix <= x1) &&
                              (loy == cy) && (hiy == cy) &&
                              (loz == cz) && (hiz == cz);
            if (!skip) {
                const int ny = hiy - loy + 1;
                const int R  = ny * (hiz - loz + 1);      // rows (z,y)
                for (int rb = 0; rb < R; rb += 64) {
                    const int r = rb + lane;
                    if (r < R) {
                        const int yy = loy + r % ny;
                        const int zz = loz + r / ny;
                        const int base = (zz * G + yy) * G;
                        const uint2 ha = dhdr[base + lox];
                        const uint2 hb = dhdr[base + hix];
                        for (u32 k = ha.x; k < hb.x + hb.y; ++k) {
                            const float4 p = dbp[k];
                            const float dx = q.x - p.x, dy = q.y - p.y, dz = q.z - p.z;
                            best = fminf(best, fmaf(dx, dx, fmaf(dy, dy, dz * dz)));
                        }
                    }
                }
#pragma unroll
                for (int m = 1; m <= 32; m <<= 1)
                    best = fminf(best, __shfl_xor(best, m, 64));
            }
            if (lane == 0) qsum += best;
        }
    }

    __shared__ float wsum[4];
    if (lane == 0) wsum[threadIdx.x >> 6] = qsum;
    __syncthreads();
    if (threadIdx.x == 0)
        atomicAdd(out, (wsum[0] + wsum[1] + wsum[2] + wsum[3]) * (1.0f / (float)NPTS));
}

// ============================================================================
extern "C" void kernel_launch(void* const* d_in, const int* in_sizes, int n_in,
                              void* d_out, int out_size, void* d_ws, size_t ws_size,
                              hipStream_t stream)
{
    const float* A = (const float*)d_in[0];   // pc0 (65536,3) f32
    const float* B = (const float*)d_in[1];   // pc1 (65536,3) f32
    float* out = (float*)d_out;               // scalar f32
    unsigned char* ws = (unsigned char*)d_ws;

    hipMemsetAsync(ws + CNTA_OFF, 0, 2u * NC * 4u, stream);   // cntA + cntB
    hipMemsetAsync(out, 0, sizeof(float), stream);

    count_kernel  <<<(2 * NPTS) / 256, 256, 0, stream>>>(A, B, ws);
    scan_kernel   <<<2, 1024, 0, stream>>>(ws);
    scatter_kernel<<<(2 * NPTS) / 256, 256, 0, stream>>>(A, B, ws);
    query_kernel  <<<(2 * NC) / 4, 256, 0, stream>>>(ws, out);
}

// Round 19
// 174.740 us; speedup vs baseline: 19.8957x; 1.1398x over previous
//
#include <hip/hip_runtime.h>

typedef unsigned int u32;

#define NPTS 65536
#define G    24
#define NC   (G*G*G)      // 13824 cells, ~4.7 pts/cell UNIFORM after CDF transform
#define CPT  14           // ceil(NC/1024) for the scan

// ws byte offsets (total ~2.32 MB)
#define CNTA_OFF 0u
#define CNTB_OFF (CNTA_OFF + NC*4u)
#define HDRA_OFF (CNTB_OFF + NC*4u)        // uint2 (start,count) per cell, 8-aligned
#define HDRB_OFF (HDRA_OFF + NC*8u)
#define SRTA_OFF (HDRB_OFF + NC*8u)
#define SRTB_OFF (SRTA_OFF + NPTS*16u)

__device__ __forceinline__ int clampi(int v, int lo, int hi) {
    return v < lo ? lo : (v > hi ? hi : v);
}

// Per-axis Gaussian CDF binning (r16-r18-validated, absmax 0.0). Monotone in
// the coordinate -> cell ranges of [q-rad, q+rad] bound the Euclidean ball.
__device__ __forceinline__ int cell1(float x) {
    const float kk = 0.07071067811865475f;   // 1/(10*sqrt(2))
    return clampi((int)(0.5f * erfcf(-x * kk) * (float)G), 0, G - 1);
}
__device__ __forceinline__ void cell3(float x, float y, float z,
                                      int& cx, int& cy, int& cz) {
    cx = cell1(x); cy = cell1(y); cz = cell1(z);
}

// ---- 1. per-cell histogram (verbatim r18) ----
__global__ __launch_bounds__(256) void count_kernel(
    const float* __restrict__ A, const float* __restrict__ B,
    unsigned char* __restrict__ ws)
{
    const int i = blockIdx.x * 256 + threadIdx.x;   // 0..131071
    const int cloud = i >= NPTS;
    const int p = i & (NPTS - 1);
    const float* __restrict__ P = cloud ? B : A;
    u32* cnt = (u32*)(ws + (cloud ? CNTB_OFF : CNTA_OFF));
    int cx, cy, cz;
    cell3(P[p * 3], P[p * 3 + 1], P[p * 3 + 2], cx, cy, cz);
    atomicAdd(&cnt[(cz * G + cy) * G + cx], 1u);
}

// ---- 2. exclusive scan -> hdr[c] = (start, count) (verbatim r18) ----
__global__ __launch_bounds__(1024) void scan_kernel(unsigned char* __restrict__ ws)
{
    const int cloud = blockIdx.x;
    const u32* cnt = (const u32*)(ws + (cloud ? CNTB_OFF : CNTA_OFF));
    uint2* hdr = (uint2*)(ws + (cloud ? HDRB_OFF : HDRA_OFF));
    const int t = threadIdx.x;

    u32 s = 0;
#pragma unroll
    for (int k = 0; k < CPT; ++k) {
        const int c = t * CPT + k;
        s += (c < NC) ? cnt[c] : 0u;
    }
    __shared__ u32 lds[1024];
    lds[t] = s;
    __syncthreads();
    for (int o = 1; o < 1024; o <<= 1) {
        const u32 v = (t >= o) ? lds[t - o] : 0u;
        __syncthreads();
        lds[t] += v;
        __syncthreads();
    }
    u32 run = lds[t] - s;
#pragma unroll
    for (int k = 0; k < CPT; ++k) {
        const int c = t * CPT + k;
        if (c < NC) {
            const u32 n = cnt[c];
            hdr[c] = make_uint2(run, n);
            run += n;
        }
    }
}

// ---- 3. scatter into cell-sorted order (verbatim r18) ----
__global__ __launch_bounds__(256) void scatter_kernel(
    const float* __restrict__ A, const float* __restrict__ B,
    unsigned char* __restrict__ ws)
{
    const int i = blockIdx.x * 256 + threadIdx.x;
    const int cloud = i >= NPTS;
    const int p = i & (NPTS - 1);
    const float* __restrict__ P = cloud ? B : A;
    u32* cnt = (u32*)(ws + (cloud ? CNTB_OFF : CNTA_OFF));
    const uint2* hdr = (const uint2*)(ws + (cloud ? HDRB_OFF : HDRA_OFF));
    float4* srt = (float4*)(ws + (cloud ? SRTB_OFF : SRTA_OFF));

    const float x = P[p * 3], y = P[p * 3 + 1], z = P[p * 3 + 2];
    int cx, cy, cz;
    cell3(x, y, z, cx, cy, cz);
    const int c = (cz * G + cy) * G + cx;
    const u32 old = atomicSub(&cnt[c], 1u);          // count .. 1, unique
    srt[hdr[c].x + old - 1u] = make_float4(x, y, z, 0.0f);
}

// ---- 4. NN query: wave per query-cell, exact two-pass ball query ----
// r18 structure (172 us, validated exact) + two instruction-count cuts,
// motivated by the counter arithmetic (~1160 wave-insts/query vs ~150
// useful): (a) runtime erfcf eliminated -- box bounds come from an LDS
// boundary table XB (erfinvf once per block) via 1-3-step walks with +-1e-3
// slack (slack only WIDENS the box -> exactness preserved); (b) TWO queries
// processed concurrently in 32-lane wave halves: per-query scalar overhead
// (sqrt, walks, loop control) and reductions (5-step, masks<=16 stay within
// the half) are paid once per half instead of once per wave.
__global__ __launch_bounds__(256) void query_kernel(
    const unsigned char* __restrict__ ws, float* __restrict__ out)
{
    __shared__ float XB[G + 1];   // Euclidean lower boundary of cell i
    if (threadIdx.x <= G) {
        float v;
        if (threadIdx.x == 0)       v = -3e37f;
        else if (threadIdx.x == G)  v =  3e37f;
        else v = 14.142135623730951f *
                 erfinvf(2.0f * (float)threadIdx.x / (float)G - 1.0f);
        XB[threadIdx.x] = v;
    }
    __syncthreads();

    const int wv   = blockIdx.x * 4 + (threadIdx.x >> 6);   // 0..27647
    const int lane = threadIdx.x & 63;
    const int half = lane >> 5;          // which query of the processed pair
    const int sub  = lane & 31;
    const int dirB = wv >= NC;       // 0: queries=A, DB=B ; 1: queries=B, DB=A
    const int c    = dirB ? wv - NC : wv;
    const int cx = c % G, cy = (c / G) % G, cz = c / (G * G);

    const uint2*  __restrict__ qhdr = (const uint2*)(ws + (dirB ? HDRB_OFF : HDRA_OFF));
    const float4* __restrict__ qp   = (const float4*)(ws + (dirB ? SRTB_OFF : SRTA_OFF));
    const uint2*  __restrict__ dhdr = (const uint2*)(ws + (dirB ? HDRA_OFF : HDRB_OFF));
    const float4* __restrict__ dbp  = (const float4*)(ws + (dirB ? SRTA_OFF : SRTB_OFF));

    const uint2 qh = qhdr[c];
    float qsum = 0.0f;

    if (qh.y != 0) {
        // own-row segment (3 x-contiguous cells), shared by all queries here
        const int x0 = max(cx - 1, 0), x1 = min(cx + 1, G - 1);
        const int rowb = (cz * G + cy) * G;
        const uint2 h0 = dhdr[rowb + x0];          // broadcast loads
        const uint2 h1 = dhdr[rowb + x1];
        const u32 s0 = h0.x, s1 = h1.x + h1.y;

        for (u32 j = 0; j < qh.y; j += 2) {
            const u32  jj  = j + (u32)half;        // this half's query
            const bool act = jj < qh.y;
            const float4 q = qp[qh.x + (act ? jj : 0u)];
            float best = 3.4e38f;

            // ---- pass 1: own row -> upper bound (32 lanes per half) ----
            for (u32 k = s0 + sub; k < s1; k += 32) {
                const float4 p = dbp[k];
                const float dx = q.x - p.x, dy = q.y - p.y, dz = q.z - p.z;
                best = fminf(best, fmaf(dx, dx, fmaf(dy, dy, dz * dz)));
            }
#pragma unroll
            for (int m = 1; m <= 16; m <<= 1)
                best = fminf(best, __shfl_xor(best, m, 64));   // in-half

            // ---- pass 2: exact ball cover; bounds via XB walks ----
            const float rad = sqrtf(best) + 1e-3f;
            const float qxl = q.x - rad - 1e-3f, qxh = q.x + rad + 1e-3f;
            const float qyl = q.y - rad - 1e-3f, qyh = q.y + rad + 1e-3f;
            const float qzl = q.z - rad - 1e-3f, qzh = q.z + rad + 1e-3f;
            int lox = cx; while (lox > 0     && XB[lox]     > qxl) --lox;
            int hix = cx; while (hix < G - 1 && XB[hix + 1] < qxh) ++hix;
            int loy = cy; while (loy > 0     && XB[loy]     > qyl) --loy;
            int hiy = cy; while (hiy < G - 1 && XB[hiy + 1] < qyh) ++hiy;
            int loz = cz; while (loz > 0     && XB[loz]     > qzl) --loz;
            int hiz = cz; while (hiz < G - 1 && XB[hiz + 1] < qzh) ++hiz;

            const bool skip = (lox >= x0) && (hix <= x1) &&
                              (loy == cy) && (hiy == cy) &&
                              (loz == cz) && (hiz == cz);
            if (!skip) {   // half-uniform condition (best/walk uniform in half)
                const int ny = hiy - loy + 1;
                const int R  = ny * (hiz - loz + 1);      // rows (z,y)
                for (int rb = 0; rb < R; rb += 32) {
                    const int r = rb + sub;
                    if (r < R) {
                        const int yy = loy + r % ny;
                        const int zz = loz + r / ny;
                        const int base = (zz * G + yy) * G;
                        const uint2 ha = dhdr[base + lox];
                        const uint2 hb = dhdr[base + hix];
                        const u32 e = hb.x + hb.y;
                        for (u32 k = ha.x; k < e; ++k) {
                            const float4 p = dbp[k];
                            const float dx = q.x - p.x, dy = q.y - p.y, dz = q.z - p.z;
                            best = fminf(best, fmaf(dx, dx, fmaf(dy, dy, dz * dz)));
                        }
                    }
                }
#pragma unroll
                for (int m = 1; m <= 16; m <<= 1)
                    best = fminf(best, __shfl_xor(best, m, 64));   // in-half
            }

            // both halves reconverged here: collect pair results on lane 0
            const float b1 = __shfl(best, 32, 64);
            if (lane == 0) {
                qsum += best;                        // query j (always valid)
                if (j + 1 < qh.y) qsum += b1;        // query j+1 if it exists
            }
        }
    }

    __shared__ float wsum[4];
    if (lane == 0) wsum[threadIdx.x >> 6] = qsum;
    __syncthreads();
    if (threadIdx.x == 0)
        atomicAdd(out, (wsum[0] + wsum[1] + wsum[2] + wsum[3]) * (1.0f / (float)NPTS));
}

// ============================================================================
extern "C" void kernel_launch(void* const* d_in, const int* in_sizes, int n_in,
                              void* d_out, int out_size, void* d_ws, size_t ws_size,
                              hipStream_t stream)
{
    const float* A = (const float*)d_in[0];   // pc0 (65536,3) f32
    const float* B = (const float*)d_in[1];   // pc1 (65536,3) f32
    float* out = (float*)d_out;               // scalar f32
    unsigned char* ws = (unsigned char*)d_ws;

    hipMemsetAsync(ws + CNTA_OFF, 0, 2u * NC * 4u, stream);   // cntA + cntB
    hipMemsetAsync(out, 0, sizeof(float), stream);

    count_kernel  <<<(2 * NPTS) / 256, 256, 0, stream>>>(A, B, ws);
    scan_kernel   <<<2, 1024, 0, stream>>>(ws);
    scatter_kernel<<<(2 * NPTS) / 256, 256, 0, stream>>>(A, B, ws);
    query_kernel  <<<(2 * NC) / 4, 256, 0, stream>>>(ws, out);
}